// Round 7
// baseline (163.847 us; speedup 1.0000x reference)
//
#include <hip/hip_runtime.h>
#include <hip/hip_bf16.h>
#include <hip/hip_cooperative_groups.h>
#include <math.h>

// out[b] = bias + sum_{i,j} W[i,j] * leaky(cf[b,i]*pf[b,j]),  leaky(z)=0.55z+0.45|z|
// Contract over j (no W transpose):
//   Gp[b,i] = sum_j pf[b,j] W[i,j],  Hp[b,i] = sum_j |pf[b,j]| W[i,j]
//   out[b]  = bias + sum_i ( 0.55 cf[b,i] Gp[b,i] + 0.45 |cf[b,i]| Hp[b,i] )
// Round-7 vs round-6: single COOPERATIVE kernel. Phase 1 = round-6 opl_main
// verbatim (partials to ws[b][blk], plain stores). threadfence + grid.sync().
// Phase 2: first 32 blocks (1 wave per batch row) reduce 512 partials + bias.
// Removes the 2nd kernel dispatch + full inter-kernel drain. Fallback to the
// proven 2-kernel path if cooperative launch is unavailable.

constexpr int B = 256, D = 1024;
constexpr int BN = 32;          // i-tile (MFMA N dim)
constexpr int JC = 64;          // j-chunk (contraction split)
constexpr int NT = D / BN;      // 32
constexpr int KC = D / JC;      // 16
constexpr int NBLK = NT * KC;   // 512 partial sets
constexpr int LDP = 72;         // padded LDS row (bf16 elems)

typedef __attribute__((ext_vector_type(8))) short bf16x8;
typedef __attribute__((ext_vector_type(4))) short bf16x4;
typedef __attribute__((ext_vector_type(4))) float f32x4;
typedef __attribute__((ext_vector_type(4))) int   int32x4;

__device__ __forceinline__ ushort f2bf(float x) {
    __hip_bfloat16 h = __float2bfloat16(x);
    return *reinterpret_cast<ushort*>(&h);
}

__device__ __forceinline__ bf16x8 cvt8(float4 lo, float4 hi) {
    bf16x8 v;
    v[0] = (short)f2bf(lo.x); v[1] = (short)f2bf(lo.y);
    v[2] = (short)f2bf(lo.z); v[3] = (short)f2bf(lo.w);
    v[4] = (short)f2bf(hi.x); v[5] = (short)f2bf(hi.y);
    v[6] = (short)f2bf(hi.z); v[7] = (short)f2bf(hi.w);
    return v;
}

// ---- phase-1 body (round-6 opl_main, verified): partials -> ws[b][blk] ----
__device__ __forceinline__ void opl_body(
    const float* __restrict__ cf, const float* __restrict__ pf,
    const float* __restrict__ W, float* __restrict__ ws)
{
    __shared__ ushort sP[B][LDP];   // pf tile  [256][72] bf16 = 36.0 KB
    __shared__ ushort sW[BN][LDP];  // W  tile  [ 32][72] bf16 =  4.5 KB

    const int nt = blockIdx.x & (NT - 1);
    const int kc = blockIdx.x >> 5;
    const int ibase = nt * BN, jbase = kc * JC;
    const int t = threadIdx.x;

    // stage W: 16 threads/row (256B runs), 4 floats each
    {
        const int r = t >> 4, c = (t & 15) * 4;
        const float4 v = *reinterpret_cast<const float4*>(&W[(size_t)(ibase + r) * D + jbase + c]);
        bf16x4 o;
        o[0] = (short)f2bf(v.x); o[1] = (short)f2bf(v.y);
        o[2] = (short)f2bf(v.z); o[3] = (short)f2bf(v.w);
        *reinterpret_cast<bf16x4*>(&sW[r][c]) = o;
    }
    // stage pf: 8 threads/row (256B runs), 8 floats each, 4 passes
    #pragma unroll
    for (int p = 0; p < 4; ++p) {
        const int r = p * 64 + (t >> 3), c = (t & 7) * 8;
        const float* src = &pf[(size_t)r * D + jbase + c];
        const float4 lo = *reinterpret_cast<const float4*>(src);
        const float4 hi = *reinterpret_cast<const float4*>(src + 4);
        *reinterpret_cast<bf16x8*>(&sP[r][c]) = cvt8(lo, hi);
    }

    // hoisted epilogue cf loads (independent of LDS; overlap staging)
    const int lane = t & 63;
    const int wid = t >> 6;
    const int mwave = wid * 32;     // 8 waves x 32 b-rows = 256 = B
    const int r16 = lane & 15;      // m/n index within fragment
    const int g = lane >> 4;        // k-block for A/B; row-group for C/D

    float cfv[2][2][4];
    #pragma unroll
    for (int mf = 0; mf < 2; ++mf)
        #pragma unroll
        for (int nf = 0; nf < 2; ++nf)
            #pragma unroll
            for (int r = 0; r < 4; ++r)
                cfv[mf][nf][r] = cf[(size_t)(mwave + mf * 16 + g * 4 + r) * D + ibase + nf * 16 + r16];

    __syncthreads();

    // MFMA: wave = 32 b-rows x 32 i-cols, K = JC
    f32x4 accG[2][2] = {};
    f32x4 accH[2][2] = {};

    #pragma unroll
    for (int ks = 0; ks < JC / 32; ++ks) {
        const int c0 = ks * 32 + g * 8;
        bf16x8 a[2], b[2];
        #pragma unroll
        for (int mf = 0; mf < 2; ++mf)
            a[mf] = *reinterpret_cast<const bf16x8*>(&sP[mwave + mf * 16 + r16][c0]);
        #pragma unroll
        for (int nf = 0; nf < 2; ++nf)
            b[nf] = *reinterpret_cast<const bf16x8*>(&sW[nf * 16 + r16][c0]);
        #pragma unroll
        for (int mf = 0; mf < 2; ++mf) {
            int32x4 ai = __builtin_bit_cast(int32x4, a[mf]);
            ai &= 0x7fff7fff;       // |pf| exactly: clear bf16 sign bits
            const bf16x8 aa = __builtin_bit_cast(bf16x8, ai);
            #pragma unroll
            for (int nf = 0; nf < 2; ++nf) {
                accG[mf][nf] = __builtin_amdgcn_mfma_f32_16x16x32_bf16(a[mf], b[nf], accG[mf][nf], 0, 0, 0);
                accH[mf][nf] = __builtin_amdgcn_mfma_f32_16x16x32_bf16(aa,    b[nf], accH[mf][nf], 0, 0, 0);
            }
        }
    }

    // epilogue: C/D col=lane&15 -> i, row=(lane>>4)*4+r -> b
    float s[2][4];
    #pragma unroll
    for (int mf = 0; mf < 2; ++mf)
        #pragma unroll
        for (int r = 0; r < 4; ++r) s[mf][r] = 0.f;

    #pragma unroll
    for (int mf = 0; mf < 2; ++mf) {
        #pragma unroll
        for (int nf = 0; nf < 2; ++nf) {
            #pragma unroll
            for (int r = 0; r < 4; ++r) {
                const float c = cfv[mf][nf][r];
                s[mf][r] = fmaf(0.55f * c, accG[mf][nf][r],
                           fmaf(0.45f * fabsf(c), accH[mf][nf][r], s[mf][r]));
            }
        }
    }
    #pragma unroll
    for (int mf = 0; mf < 2; ++mf) {
        #pragma unroll
        for (int r = 0; r < 4; ++r) {
            float v = s[mf][r];
            v += __shfl_xor(v, 1);
            v += __shfl_xor(v, 2);
            v += __shfl_xor(v, 4);
            v += __shfl_xor(v, 8);
            s[mf][r] = v;
        }
    }
    if (r16 == 0) {
        #pragma unroll
        for (int mf = 0; mf < 2; ++mf)
            #pragma unroll
            for (int r = 0; r < 4; ++r)
                ws[(size_t)(mwave + mf * 16 + g * 4 + r) * NBLK + blockIdx.x] = s[mf][r];
    }
}

// ---- cooperative single-kernel: phase1 + grid sync + phase2 reduce ----
__global__ __launch_bounds__(512) void opl_coop(
    const float* __restrict__ cf, const float* __restrict__ pf,
    const float* __restrict__ W, float* __restrict__ ws,
    const float* __restrict__ bias, float* __restrict__ out)
{
    opl_body(cf, pf, W, ws);

    __threadfence();
    cooperative_groups::this_grid().sync();

    // phase 2: blocks 0..31, one wave per batch row (32 blocks x 8 waves = 256)
    if (blockIdx.x < 32) {
        const int wid = threadIdx.x >> 6, lane = threadIdx.x & 63;
        const int b = blockIdx.x * 8 + wid;
        const float* p = ws + (size_t)b * NBLK;
        float s = 0.f;
        #pragma unroll
        for (int k = 0; k < NBLK / 64; ++k) s += p[lane + k * 64];
        #pragma unroll
        for (int off = 1; off < 64; off <<= 1) s += __shfl_xor(s, off);
        if (lane == 0) out[b] = s + bias[0];
    }
}

// ---- fallback: proven round-6 two-kernel path ----
__global__ __launch_bounds__(512) void opl_main(
    const float* __restrict__ cf, const float* __restrict__ pf,
    const float* __restrict__ W, float* __restrict__ ws)
{
    opl_body(cf, pf, W, ws);
}

__global__ __launch_bounds__(256) void opl_reduce(
    const float* __restrict__ ws, const float* __restrict__ bias,
    float* __restrict__ out)
{
    const int wid = threadIdx.x >> 6, lane = threadIdx.x & 63;
    const int b = blockIdx.x * 4 + wid;
    const float* p = ws + (size_t)b * NBLK;
    float s = 0.f;
    #pragma unroll
    for (int k = 0; k < NBLK / 64; ++k) s += p[lane + k * 64];
    #pragma unroll
    for (int off = 1; off < 64; off <<= 1) s += __shfl_xor(s, off);
    if (lane == 0) out[b] = s + bias[0];
}

extern "C" void kernel_launch(void* const* d_in, const int* in_sizes, int n_in,
                              void* d_out, int out_size, void* d_ws, size_t ws_size,
                              hipStream_t stream) {
    const float* cf   = (const float*)d_in[0];
    const float* pf   = (const float*)d_in[1];
    const float* W    = (const float*)d_in[2];
    const float* bias = (const float*)d_in[3];
    float* out = (float*)d_out;
    float* ws  = (float*)d_ws;   // B * NBLK * 4 = 512 KB, fully rewritten each call

    void* args[] = {(void*)&cf, (void*)&pf, (void*)&W, (void*)&ws,
                    (void*)&bias, (void*)&out};
    hipError_t err = hipLaunchCooperativeKernel(
        reinterpret_cast<void*>(opl_coop), dim3(NT * KC), dim3(512),
        args, 0, stream);
    if (err != hipSuccess) {
        // fallback: two-dispatch path (round 6, verified)
        opl_main<<<NT * KC, 512, 0, stream>>>(cf, pf, W, ws);
        opl_reduce<<<B / 4, 256, 0, stream>>>(ws, bias, out);
    }
}

// Round 8
// 50.290 us; speedup vs baseline: 3.2580x; 3.2580x over previous
//
#include <hip/hip_runtime.h>
#include <hip/hip_bf16.h>
#include <math.h>

// out[b] = bias + sum_{i,j} W[i,j] * leaky(cf[b,i]*pf[b,j]),  leaky(z)=0.55z+0.45|z|
// Bilinear: out[b] = bias + 0.55 cf[b]^T W pf[b] + 0.45 |cf[b]|^T W |pf[b]|
// Per-block (i,j)-rectangle partials are additive. Round-8 vs round-6:
// single dispatch; the cross-block reduction is completion-driven (atomic
// counters + threadfence), hierarchical (16-block groups -> 32 group sums ->
// final), so reducers overlap the main tail. NO grid.sync (round-7 showed the
// cooperative barrier costs ~130us). Counters zeroed via hipMemsetAsync node.

constexpr int B = 256, D = 1024;
constexpr int BN = 32;            // i-tile (MFMA N dim)
constexpr int JC = 64;            // j-chunk (contraction split)
constexpr int NT = D / BN;        // 32
constexpr int KC = D / JC;        // 16
constexpr int NBLK = NT * KC;     // 512 blocks / partial sets
constexpr int GRP = 16, NGRP = NBLK / GRP;  // 32 groups of 16
constexpr int LDP = 72;           // padded LDS row (bf16 elems)

typedef __attribute__((ext_vector_type(8))) short bf16x8;
typedef __attribute__((ext_vector_type(4))) short bf16x4;
typedef __attribute__((ext_vector_type(4))) float f32x4;
typedef __attribute__((ext_vector_type(4))) int   int32x4;

__device__ __forceinline__ ushort f2bf(float x) {
    __hip_bfloat16 h = __float2bfloat16(x);
    return *reinterpret_cast<ushort*>(&h);
}

__device__ __forceinline__ bf16x8 cvt8(float4 lo, float4 hi) {
    bf16x8 v;
    v[0] = (short)f2bf(lo.x); v[1] = (short)f2bf(lo.y);
    v[2] = (short)f2bf(lo.z); v[3] = (short)f2bf(lo.w);
    v[4] = (short)f2bf(hi.x); v[5] = (short)f2bf(hi.y);
    v[6] = (short)f2bf(hi.z); v[7] = (short)f2bf(hi.w);
    return v;
}

// ws layout (floats): part[NBLK][B] | ws2[NGRP][B] | cnt[NGRP+1] (ints)
constexpr size_t PART_F = (size_t)NBLK * B;           // 131072
constexpr size_t WS2_F  = (size_t)NGRP * B;           // 8192
constexpr size_t CNT_OFF_F = PART_F + WS2_F;          // float offset of counters
constexpr size_t WS_NEED = (CNT_OFF_F + NGRP + 1) * 4;

__global__ __launch_bounds__(512) void opl_fused(
    const float* __restrict__ cf, const float* __restrict__ pf,
    const float* __restrict__ W, float* __restrict__ ws,
    const float* __restrict__ bias, float* __restrict__ out)
{
    __shared__ ushort sP[B][LDP];   // pf tile  [256][72] bf16 = 36.0 KB
    __shared__ ushort sW[BN][LDP];  // W  tile  [ 32][72] bf16 =  4.5 KB
    __shared__ int sflag;

    float* part = ws;
    float* ws2  = ws + PART_F;
    int*   cnt  = (int*)(ws + CNT_OFF_F);

    const int nt = blockIdx.x & (NT - 1);
    const int kc = blockIdx.x >> 5;
    const int ibase = nt * BN, jbase = kc * JC;
    const int t = threadIdx.x;

    // ---- stage W: 16 threads/row (256B runs), 4 floats each ----
    {
        const int r = t >> 4, c = (t & 15) * 4;
        const float4 v = *reinterpret_cast<const float4*>(&W[(size_t)(ibase + r) * D + jbase + c]);
        bf16x4 o;
        o[0] = (short)f2bf(v.x); o[1] = (short)f2bf(v.y);
        o[2] = (short)f2bf(v.z); o[3] = (short)f2bf(v.w);
        *reinterpret_cast<bf16x4*>(&sW[r][c]) = o;
    }
    // ---- stage pf: 8 threads/row (256B runs), 8 floats each, 4 passes ----
    #pragma unroll
    for (int p = 0; p < 4; ++p) {
        const int r = p * 64 + (t >> 3), c = (t & 7) * 8;
        const float* src = &pf[(size_t)r * D + jbase + c];
        const float4 lo = *reinterpret_cast<const float4*>(src);
        const float4 hi = *reinterpret_cast<const float4*>(src + 4);
        *reinterpret_cast<bf16x8*>(&sP[r][c]) = cvt8(lo, hi);
    }

    // ---- hoisted epilogue cf loads (independent of LDS; overlap staging) ----
    const int lane = t & 63;
    const int wid = t >> 6;
    const int mwave = wid * 32;     // 8 waves x 32 b-rows = 256 = B
    const int r16 = lane & 15;      // m/n index within fragment
    const int g = lane >> 4;        // k-block for A/B; row-group for C/D

    float cfv[2][2][4];
    #pragma unroll
    for (int mf = 0; mf < 2; ++mf)
        #pragma unroll
        for (int nf = 0; nf < 2; ++nf)
            #pragma unroll
            for (int r = 0; r < 4; ++r)
                cfv[mf][nf][r] = cf[(size_t)(mwave + mf * 16 + g * 4 + r) * D + ibase + nf * 16 + r16];

    __syncthreads();

    // ---- MFMA: wave = 32 b-rows x 32 i-cols, K = JC ----
    f32x4 accG[2][2] = {};
    f32x4 accH[2][2] = {};

    #pragma unroll
    for (int ks = 0; ks < JC / 32; ++ks) {
        const int c0 = ks * 32 + g * 8;
        bf16x8 a[2], b[2];
        #pragma unroll
        for (int mf = 0; mf < 2; ++mf)
            a[mf] = *reinterpret_cast<const bf16x8*>(&sP[mwave + mf * 16 + r16][c0]);
        #pragma unroll
        for (int nf = 0; nf < 2; ++nf)
            b[nf] = *reinterpret_cast<const bf16x8*>(&sW[nf * 16 + r16][c0]);
        #pragma unroll
        for (int mf = 0; mf < 2; ++mf) {
            int32x4 ai = __builtin_bit_cast(int32x4, a[mf]);
            ai &= 0x7fff7fff;       // |pf| exactly: clear bf16 sign bits
            const bf16x8 aa = __builtin_bit_cast(bf16x8, ai);
            #pragma unroll
            for (int nf = 0; nf < 2; ++nf) {
                accG[mf][nf] = __builtin_amdgcn_mfma_f32_16x16x32_bf16(a[mf], b[nf], accG[mf][nf], 0, 0, 0);
                accH[mf][nf] = __builtin_amdgcn_mfma_f32_16x16x32_bf16(aa,    b[nf], accH[mf][nf], 0, 0, 0);
            }
        }
    }

    // ---- epilogue: C/D col=lane&15 -> i, row=(lane>>4)*4+r -> b ----
    float s[2][4];
    #pragma unroll
    for (int mf = 0; mf < 2; ++mf)
        #pragma unroll
        for (int r = 0; r < 4; ++r) s[mf][r] = 0.f;

    #pragma unroll
    for (int mf = 0; mf < 2; ++mf) {
        #pragma unroll
        for (int nf = 0; nf < 2; ++nf) {
            #pragma unroll
            for (int r = 0; r < 4; ++r) {
                const float c = cfv[mf][nf][r];
                s[mf][r] = fmaf(0.55f * c, accG[mf][nf][r],
                           fmaf(0.45f * fabsf(c), accH[mf][nf][r], s[mf][r]));
            }
        }
    }
    #pragma unroll
    for (int mf = 0; mf < 2; ++mf) {
        #pragma unroll
        for (int r = 0; r < 4; ++r) {
            float v = s[mf][r];
            v += __shfl_xor(v, 1);
            v += __shfl_xor(v, 2);
            v += __shfl_xor(v, 4);
            v += __shfl_xor(v, 8);
            s[mf][r] = v;
        }
    }
    // per-block partials, vectorized: part[blk][b]
    if (r16 == 0) {
        float* dst = part + (size_t)blockIdx.x * B;
        #pragma unroll
        for (int mf = 0; mf < 2; ++mf) {
            f32x4 v = {s[mf][0], s[mf][1], s[mf][2], s[mf][3]};
            *reinterpret_cast<f32x4*>(&dst[mwave + mf * 16 + g * 4]) = v;
        }
    }

    // ---- completion-driven hierarchical reduction ----
    const int grp = blockIdx.x >> 4;   // 16 blocks per group
    __syncthreads();                    // drains all stores (vmcnt0 pre-barrier)
    if (t == 0) {
        __threadfence();                // release: push dirty L2 to coherence pt
        sflag = (atomicAdd(&cnt[grp], 1) == GRP - 1) ? 1 : 0;
    }
    __syncthreads();
    if (sflag) {                        // last block of the group: reduce it
        __threadfence();                // acquire
        if (t < B) {
            float acc = 0.f;
            #pragma unroll
            for (int k = 0; k < GRP; ++k)
                acc += part[(size_t)(grp * GRP + k) * B + t];   // coalesced
            ws2[(size_t)grp * B + t] = acc;
        }
        __syncthreads();
        if (t == 0) {
            __threadfence();            // release ws2
            sflag = (atomicAdd(&cnt[NGRP], 1) == NGRP - 1) ? 1 : 0;
        }
        __syncthreads();
        if (sflag) {                    // last group: final 32x256 reduce
            __threadfence();            // acquire
            if (t < B) {
                float acc = 0.f;
                #pragma unroll
                for (int g2 = 0; g2 < NGRP; ++g2)
                    acc += ws2[(size_t)g2 * B + t];             // coalesced
                out[t] = acc + bias[0];
            }
        }
    }
}

// ---- fallback (round-1 verified pure-VALU path) if ws too small ----
__global__ __launch_bounds__(256) void opl_init_fb(float* __restrict__ out,
                                                   const float* __restrict__ bias) {
    out[threadIdx.x] = bias[0];
}

__global__ __launch_bounds__(256, 2) void opl_valu_fb(
    const float* __restrict__ cf, const float* __restrict__ pf,
    const float* __restrict__ W, float* __restrict__ out)
{
    constexpr int BM = 64, BNf = 64, BK = 32, FKC = 128;
    const int bid = blockIdx.x;
    const int mt = bid & 3, ntb = (bid >> 2) & 15, kcb = bid >> 6;
    const int mbase = mt * BM, nbase = ntb * BNf, kbase = kcb * FKC;
    __shared__ float sWf[BK][BNf];
    __shared__ float sC[BK][BM + 4];
    const int tid = threadIdx.x;
    const int tx = tid & 15, ty = tid >> 4;
    const int wr = tid >> 4, wc = (tid & 15) * 4;
    const int cb = tid >> 3, ci = (tid & 7) * 4;
    float accG[4][4] = {{0.f}}, accH[4][4] = {{0.f}};
    for (int k0 = 0; k0 < FKC; k0 += BK) {
        const int kg = kbase + k0;
        const float4 w0 = *reinterpret_cast<const float4*>(&W[(size_t)(kg + wr) * D + nbase + wc]);
        const float4 w1 = *reinterpret_cast<const float4*>(&W[(size_t)(kg + wr + 16) * D + nbase + wc]);
        const float4 c0 = *reinterpret_cast<const float4*>(&cf[(size_t)(mbase + cb) * D + kg + ci]);
        const float4 c1 = *reinterpret_cast<const float4*>(&cf[(size_t)(mbase + cb + 32) * D + kg + ci]);
        *reinterpret_cast<float4*>(&sWf[wr][wc]) = w0;
        *reinterpret_cast<float4*>(&sWf[wr + 16][wc]) = w1;
        sC[ci + 0][cb] = c0.x; sC[ci + 1][cb] = c0.y;
        sC[ci + 2][cb] = c0.z; sC[ci + 3][cb] = c0.w;
        sC[ci + 0][cb + 32] = c1.x; sC[ci + 1][cb + 32] = c1.y;
        sC[ci + 2][cb + 32] = c1.z; sC[ci + 3][cb + 32] = c1.w;
        __syncthreads();
        #pragma unroll
        for (int k = 0; k < BK; ++k) {
            const float4 wv = *reinterpret_cast<const float4*>(&sWf[k][tx * 4]);
            const float4 cv = *reinterpret_cast<const float4*>(&sC[k][ty * 4]);
            const float w[4] = {wv.x, wv.y, wv.z, wv.w};
            const float c[4] = {cv.x, cv.y, cv.z, cv.w};
            #pragma unroll
            for (int r = 0; r < 4; ++r) {
                const float cc = c[r], aa = fabsf(cc);
                #pragma unroll
                for (int q = 0; q < 4; ++q) {
                    accG[r][q] = fmaf(cc, w[q], accG[r][q]);
                    accH[r][q] = fmaf(aa, w[q], accH[r][q]);
                }
            }
        }
        __syncthreads();
    }
    float sr[4];
    #pragma unroll
    for (int r = 0; r < 4; ++r) {
        const float4 pv = *reinterpret_cast<const float4*>(&pf[(size_t)(mbase + ty * 4 + r) * D + nbase + tx * 4]);
        const float p[4] = {pv.x, pv.y, pv.z, pv.w};
        float acc = 0.f;
        #pragma unroll
        for (int q = 0; q < 4; ++q)
            acc += 0.55f * p[q] * accG[r][q] + 0.45f * fabsf(p[q]) * accH[r][q];
        sr[r] = acc;
    }
    #pragma unroll
    for (int r = 0; r < 4; ++r) {
        sr[r] += __shfl_xor(sr[r], 1);
        sr[r] += __shfl_xor(sr[r], 2);
        sr[r] += __shfl_xor(sr[r], 4);
        sr[r] += __shfl_xor(sr[r], 8);
    }
    if (tx == 0) {
        #pragma unroll
        for (int r = 0; r < 4; ++r)
            atomicAdd(&out[mbase + ty * 4 + r], sr[r]);
    }
}

extern "C" void kernel_launch(void* const* d_in, const int* in_sizes, int n_in,
                              void* d_out, int out_size, void* d_ws, size_t ws_size,
                              hipStream_t stream) {
    const float* cf   = (const float*)d_in[0];
    const float* pf   = (const float*)d_in[1];
    const float* W    = (const float*)d_in[2];
    const float* bias = (const float*)d_in[3];
    float* out = (float*)d_out;
    float* ws  = (float*)d_ws;

    if (ws_size >= WS_NEED) {
        int* cnt = (int*)(ws + CNT_OFF_F);
        hipMemsetAsync(cnt, 0, (NGRP + 1) * sizeof(int), stream);
        opl_fused<<<NBLK, 512, 0, stream>>>(cf, pf, W, ws, bias, out);
    } else {
        opl_init_fb<<<1, 256, 0, stream>>>(out, bias);
        opl_valu_fb<<<512, 256, 0, stream>>>(cf, pf, W, out);
    }
}

// Round 9
// 12.072 us; speedup vs baseline: 13.5730x; 4.1660x over previous
//
#include <hip/hip_runtime.h>
#include <hip/hip_bf16.h>
#include <math.h>

// out[b] = bias + sum_{i,j} W[i,j] * leaky(cf[b,i]*pf[b,j]),  leaky(z)=0.55z+0.45|z|
// Contract over j (no W transpose):
//   Gp[b,i] = sum_j pf[b,j] W[i,j],  Hp[b,i] = sum_j |pf[b,j]| W[i,j]
//   out[b]  = bias + sum_i ( 0.55 cf[b,i] Gp[b,i] + 0.45 |cf[b,i]| Hp[b,i] )
// Round-9 vs round-6: two-dispatch skeleton kept (rounds 4/7/8 proved in-kernel
// cross-block coordination — atomics, grid.sync, threadfence — costs >=40us).
// Batch dim split (BM=128): 1024 blocks x 256 threads, 22.5KB LDS -> ~6-7
// blocks/CU of independent stage->sync->MFMA pipelines (round 5/6 showed
// waves-within-a-block isn't the lever; block count is the remaining one).

constexpr int B = 256, D = 1024;
constexpr int BN = 32;            // i-tile (MFMA N dim)
constexpr int JC = 64;            // j-chunk (contraction split)
constexpr int BM = 128;           // b-rows per block (batch split)
constexpr int NT = D / BN;        // 32
constexpr int KC = D / JC;        // 16
constexpr int NBH = B / BM;       // 2
constexpr int NBLK = NT * KC * NBH;  // 1024 blocks
constexpr int NPART = NT * KC;    // 512 partials per batch row
constexpr int LDP = 72;           // padded LDS row (bf16 elems)

typedef __attribute__((ext_vector_type(8))) short bf16x8;
typedef __attribute__((ext_vector_type(4))) float f32x4;
typedef __attribute__((ext_vector_type(4))) int   int32x4;

__device__ __forceinline__ ushort f2bf(float x) {
    __hip_bfloat16 h = __float2bfloat16(x);
    return *reinterpret_cast<ushort*>(&h);
}

__device__ __forceinline__ bf16x8 cvt8(float4 lo, float4 hi) {
    bf16x8 v;
    v[0] = (short)f2bf(lo.x); v[1] = (short)f2bf(lo.y);
    v[2] = (short)f2bf(lo.z); v[3] = (short)f2bf(lo.w);
    v[4] = (short)f2bf(hi.x); v[5] = (short)f2bf(hi.y);
    v[6] = (short)f2bf(hi.z); v[7] = (short)f2bf(hi.w);
    return v;
}

__global__ __launch_bounds__(256, 4) void opl_main(
    const float* __restrict__ cf, const float* __restrict__ pf,
    const float* __restrict__ W, float* __restrict__ ws)
{
    __shared__ ushort sP[BM][LDP];  // pf half-tile [128][72] bf16 = 18.0 KB
    __shared__ ushort sW[BN][LDP];  // W  tile      [ 32][72] bf16 =  4.5 KB

    const int nt = blockIdx.x & (NT - 1);
    const int kc = (blockIdx.x >> 5) & (KC - 1);
    const int bh = blockIdx.x >> 9;
    const int ibase = nt * BN, jbase = kc * JC, bbase = bh * BM;
    const int t = threadIdx.x;

    // ---- stage W: 8 threads/row (256B runs), 8 floats each, one pass ----
    {
        const int r = t >> 3, c = (t & 7) * 8;
        const float* src = &W[(size_t)(ibase + r) * D + jbase + c];
        const float4 lo = *reinterpret_cast<const float4*>(src);
        const float4 hi = *reinterpret_cast<const float4*>(src + 4);
        *reinterpret_cast<bf16x8*>(&sW[r][c]) = cvt8(lo, hi);
    }
    // ---- stage pf half: 8 threads/row, 8 floats each, 4 passes ----
    #pragma unroll
    for (int p = 0; p < 4; ++p) {
        const int r = p * 32 + (t >> 3), c = (t & 7) * 8;
        const float* src = &pf[(size_t)(bbase + r) * D + jbase + c];
        const float4 lo = *reinterpret_cast<const float4*>(src);
        const float4 hi = *reinterpret_cast<const float4*>(src + 4);
        *reinterpret_cast<bf16x8*>(&sP[r][c]) = cvt8(lo, hi);
    }

    // ---- hoisted epilogue cf loads (independent of LDS; overlap staging) ----
    const int lane = t & 63;
    const int wid = t >> 6;
    const int mloc = wid * 32;      // 4 waves x 32 local b-rows = 128 = BM
    const int r16 = lane & 15;      // m/n index within fragment
    const int g = lane >> 4;        // k-block for A/B; row-group for C/D

    float cfv[2][2][4];
    #pragma unroll
    for (int mf = 0; mf < 2; ++mf)
        #pragma unroll
        for (int nf = 0; nf < 2; ++nf)
            #pragma unroll
            for (int r = 0; r < 4; ++r)
                cfv[mf][nf][r] = cf[(size_t)(bbase + mloc + mf * 16 + g * 4 + r) * D
                                    + ibase + nf * 16 + r16];

    __syncthreads();

    // ---- MFMA: wave = 32 b-rows x 32 i-cols, K = JC ----
    f32x4 accG[2][2] = {};
    f32x4 accH[2][2] = {};

    #pragma unroll
    for (int ks = 0; ks < JC / 32; ++ks) {
        const int c0 = ks * 32 + g * 8;
        bf16x8 a[2], b[2];
        #pragma unroll
        for (int mf = 0; mf < 2; ++mf)
            a[mf] = *reinterpret_cast<const bf16x8*>(&sP[mloc + mf * 16 + r16][c0]);
        #pragma unroll
        for (int nf = 0; nf < 2; ++nf)
            b[nf] = *reinterpret_cast<const bf16x8*>(&sW[nf * 16 + r16][c0]);
        #pragma unroll
        for (int mf = 0; mf < 2; ++mf) {
            int32x4 ai = __builtin_bit_cast(int32x4, a[mf]);
            ai &= 0x7fff7fff;       // |pf| exactly: clear bf16 sign bits
            const bf16x8 aa = __builtin_bit_cast(bf16x8, ai);
            #pragma unroll
            for (int nf = 0; nf < 2; ++nf) {
                accG[mf][nf] = __builtin_amdgcn_mfma_f32_16x16x32_bf16(a[mf], b[nf], accG[mf][nf], 0, 0, 0);
                accH[mf][nf] = __builtin_amdgcn_mfma_f32_16x16x32_bf16(aa,    b[nf], accH[mf][nf], 0, 0, 0);
            }
        }
    }

    // ---- epilogue: C/D col=lane&15 -> i, row=(lane>>4)*4+r -> b ----
    float s[2][4];
    #pragma unroll
    for (int mf = 0; mf < 2; ++mf)
        #pragma unroll
        for (int r = 0; r < 4; ++r) s[mf][r] = 0.f;

    #pragma unroll
    for (int mf = 0; mf < 2; ++mf) {
        #pragma unroll
        for (int nf = 0; nf < 2; ++nf) {
            #pragma unroll
            for (int r = 0; r < 4; ++r) {
                const float c = cfv[mf][nf][r];
                s[mf][r] = fmaf(0.55f * c, accG[mf][nf][r],
                           fmaf(0.45f * fabsf(c), accH[mf][nf][r], s[mf][r]));
            }
        }
    }
    #pragma unroll
    for (int mf = 0; mf < 2; ++mf) {
        #pragma unroll
        for (int r = 0; r < 4; ++r) {
            float v = s[mf][r];
            v += __shfl_xor(v, 1);
            v += __shfl_xor(v, 2);
            v += __shfl_xor(v, 4);
            v += __shfl_xor(v, 8);
            s[mf][r] = v;
        }
    }
    // partials: ws[b][nt*KC+kc]; both bh halves write disjoint b -> no overlap
    if (r16 == 0) {
        const int flat = nt * KC + kc;
        #pragma unroll
        for (int mf = 0; mf < 2; ++mf)
            #pragma unroll
            for (int r = 0; r < 4; ++r)
                ws[(size_t)(bbase + mloc + mf * 16 + g * 4 + r) * NPART + flat] = s[mf][r];
    }
}

// one wave per batch row: sum 512 contiguous partials + bias
__global__ __launch_bounds__(256) void opl_reduce(
    const float* __restrict__ ws, const float* __restrict__ bias,
    float* __restrict__ out)
{
    const int wid = threadIdx.x >> 6, lane = threadIdx.x & 63;
    const int b = blockIdx.x * 4 + wid;
    const float* p = ws + (size_t)b * NPART;
    float s = 0.f;
    #pragma unroll
    for (int k = 0; k < NPART / 64; ++k) s += p[lane + k * 64];
    #pragma unroll
    for (int off = 1; off < 64; off <<= 1) s += __shfl_xor(s, off);
    if (lane == 0) out[b] = s + bias[0];
}

// ---- fallback (round-1 verified pure-VALU path) if ws too small ----
__global__ __launch_bounds__(256) void opl_init_fb(float* __restrict__ out,
                                                   const float* __restrict__ bias) {
    out[threadIdx.x] = bias[0];
}

__global__ __launch_bounds__(256, 2) void opl_valu_fb(
    const float* __restrict__ cf, const float* __restrict__ pf,
    const float* __restrict__ W, float* __restrict__ out)
{
    constexpr int FBM = 64, FBN = 64, FBK = 32, FKC = 128;
    const int bid = blockIdx.x;
    const int mt = bid & 3, ntb = (bid >> 2) & 15, kcb = bid >> 6;
    const int mbase = mt * FBM, nbase = ntb * FBN, kbase = kcb * FKC;
    __shared__ float sWf[FBK][FBN];
    __shared__ float sC[FBK][FBM + 4];
    const int tid = threadIdx.x;
    const int tx = tid & 15, ty = tid >> 4;
    const int wr = tid >> 4, wc = (tid & 15) * 4;
    const int cb = tid >> 3, ci = (tid & 7) * 4;
    float accG[4][4] = {{0.f}}, accH[4][4] = {{0.f}};
    for (int k0 = 0; k0 < FKC; k0 += FBK) {
        const int kg = kbase + k0;
        const float4 w0 = *reinterpret_cast<const float4*>(&W[(size_t)(kg + wr) * D + nbase + wc]);
        const float4 w1 = *reinterpret_cast<const float4*>(&W[(size_t)(kg + wr + 16) * D + nbase + wc]);
        const float4 c0 = *reinterpret_cast<const float4*>(&cf[(size_t)(mbase + cb) * D + kg + ci]);
        const float4 c1 = *reinterpret_cast<const float4*>(&cf[(size_t)(mbase + cb + 32) * D + kg + ci]);
        *reinterpret_cast<float4*>(&sWf[wr][wc]) = w0;
        *reinterpret_cast<float4*>(&sWf[wr + 16][wc]) = w1;
        sC[ci + 0][cb] = c0.x; sC[ci + 1][cb] = c0.y;
        sC[ci + 2][cb] = c0.z; sC[ci + 3][cb] = c0.w;
        sC[ci + 0][cb + 32] = c1.x; sC[ci + 1][cb + 32] = c1.y;
        sC[ci + 2][cb + 32] = c1.z; sC[ci + 3][cb + 32] = c1.w;
        __syncthreads();
        #pragma unroll
        for (int k = 0; k < FBK; ++k) {
            const float4 wv = *reinterpret_cast<const float4*>(&sWf[k][tx * 4]);
            const float4 cv = *reinterpret_cast<const float4*>(&sC[k][ty * 4]);
            const float w[4] = {wv.x, wv.y, wv.z, wv.w};
            const float c[4] = {cv.x, cv.y, cv.z, cv.w};
            #pragma unroll
            for (int r = 0; r < 4; ++r) {
                const float cc = c[r], aa = fabsf(cc);
                #pragma unroll
                for (int q = 0; q < 4; ++q) {
                    accG[r][q] = fmaf(cc, w[q], accG[r][q]);
                    accH[r][q] = fmaf(aa, w[q], accH[r][q]);
                }
            }
        }
        __syncthreads();
    }
    float sr[4];
    #pragma unroll
    for (int r = 0; r < 4; ++r) {
        const float4 pv = *reinterpret_cast<const float4*>(&pf[(size_t)(mbase + ty * 4 + r) * D + nbase + tx * 4]);
        const float p[4] = {pv.x, pv.y, pv.z, pv.w};
        float acc = 0.f;
        #pragma unroll
        for (int q = 0; q < 4; ++q)
            acc += 0.55f * p[q] * accG[r][q] + 0.45f * fabsf(p[q]) * accH[r][q];
        sr[r] = acc;
    }
    #pragma unroll
    for (int r = 0; r < 4; ++r) {
        sr[r] += __shfl_xor(sr[r], 1);
        sr[r] += __shfl_xor(sr[r], 2);
        sr[r] += __shfl_xor(sr[r], 4);
        sr[r] += __shfl_xor(sr[r], 8);
    }
    if (tx == 0) {
        #pragma unroll
        for (int r = 0; r < 4; ++r)
            atomicAdd(&out[mbase + ty * 4 + r], sr[r]);
    }
}

extern "C" void kernel_launch(void* const* d_in, const int* in_sizes, int n_in,
                              void* d_out, int out_size, void* d_ws, size_t ws_size,
                              hipStream_t stream) {
    const float* cf   = (const float*)d_in[0];
    const float* pf   = (const float*)d_in[1];
    const float* W    = (const float*)d_in[2];
    const float* bias = (const float*)d_in[3];
    float* out = (float*)d_out;
    float* ws  = (float*)d_ws;   // B * NPART * 4 = 512 KB, fully rewritten each call

    if (ws_size >= (size_t)B * NPART * sizeof(float)) {
        opl_main<<<NBLK, 256, 0, stream>>>(cf, pf, W, ws);
        opl_reduce<<<B / 4, 256, 0, stream>>>(ws, bias, out);
    } else {
        opl_init_fb<<<1, 256, 0, stream>>>(out, bias);
        opl_valu_fb<<<512, 256, 0, stream>>>(cf, pf, W, out);
    }
}

// Round 10
// 11.457 us; speedup vs baseline: 14.3006x; 1.0536x over previous
//
#include <hip/hip_runtime.h>
#include <hip/hip_bf16.h>
#include <math.h>

// out[b] = bias + sum_{i,j} W[i,j] * leaky(cf[b,i]*pf[b,j]),  leaky(z)=0.55z+0.45|z|
// Contract over j (no W transpose):
//   Gp[b,i] = sum_j pf[b,j] W[i,j],  Hp[b,i] = sum_j |pf[b,j]| W[i,j]
//   out[b]  = bias + sum_i ( 0.55 cf[b,i] Gp[b,i] + 0.45 |cf[b,i]| Hp[b,i] )
// Round-10 vs round-9: minimize aggregate L2 tile traffic. BN 32->64 halves
// pf re-stages (NT 32->16): tile reads 56MB -> 40MB. Grid 512x256t, 27.6KB
// LDS, 2 blocks/CU all-resident. Partials per b halve (512->256). Block id
// ordered so the 16 nt-blocks sharing a pf tile are XCD-co-resident
// (bid%8 == (2kc+bh)%8). Two-dispatch skeleton kept (rounds 4/7/8: in-kernel
// cross-block coordination costs >=40us on this chip).

constexpr int B = 256, D = 1024;
constexpr int BN = 64;            // i-tile (MFMA N dim)
constexpr int JC = 64;            // j-chunk (contraction split)
constexpr int BM = 128;           // b-rows per block
constexpr int NT = D / BN;        // 16
constexpr int KC = D / JC;        // 16
constexpr int NBH = B / BM;       // 2
constexpr int NBLK = NT * KC * NBH;  // 512 blocks
constexpr int NPART = NT * KC;    // 256 partials per batch row
constexpr int LDP = 72;           // padded LDS row (bf16 elems)

typedef __attribute__((ext_vector_type(8))) short bf16x8;
typedef __attribute__((ext_vector_type(4))) float f32x4;
typedef __attribute__((ext_vector_type(4))) int   int32x4;

__device__ __forceinline__ ushort f2bf(float x) {
    __hip_bfloat16 h = __float2bfloat16(x);
    return *reinterpret_cast<ushort*>(&h);
}

__device__ __forceinline__ bf16x8 cvt8(float4 lo, float4 hi) {
    bf16x8 v;
    v[0] = (short)f2bf(lo.x); v[1] = (short)f2bf(lo.y);
    v[2] = (short)f2bf(lo.z); v[3] = (short)f2bf(lo.w);
    v[4] = (short)f2bf(hi.x); v[5] = (short)f2bf(hi.y);
    v[6] = (short)f2bf(hi.z); v[7] = (short)f2bf(hi.w);
    return v;
}

__global__ __launch_bounds__(256, 2) void opl_main(
    const float* __restrict__ cf, const float* __restrict__ pf,
    const float* __restrict__ W, float* __restrict__ ws)
{
    __shared__ ushort sP[BM][LDP];  // pf tile [128][72] bf16 = 18.0 KB
    __shared__ ushort sW[BN][LDP];  // W  tile [ 64][72] bf16 =  9.0 KB

    // bid = nt*32 + kc*2 + bh: the 16 nt-blocks sharing a pf tile have equal
    // bid mod 32 (hence equal mod 8) -> same XCD under round-robin dispatch.
    const int bid = blockIdx.x;
    const int nt = bid >> 5;
    const int kc = (bid & 31) >> 1;
    const int bh = bid & 1;
    const int ibase = nt * BN, jbase = kc * JC, bbase = bh * BM;
    const int t = threadIdx.x;

    // ---- stage W: 64x64 f32, 8 threads/row (256B runs), 2 passes ----
    #pragma unroll
    for (int p = 0; p < 2; ++p) {
        const int r = p * 32 + (t >> 3), c = (t & 7) * 8;
        const float* src = &W[(size_t)(ibase + r) * D + jbase + c];
        const float4 lo = *reinterpret_cast<const float4*>(src);
        const float4 hi = *reinterpret_cast<const float4*>(src + 4);
        *reinterpret_cast<bf16x8*>(&sW[r][c]) = cvt8(lo, hi);
    }
    // ---- stage pf half: 128x64 f32, 8 threads/row, 4 passes ----
    #pragma unroll
    for (int p = 0; p < 4; ++p) {
        const int r = p * 32 + (t >> 3), c = (t & 7) * 8;
        const float* src = &pf[(size_t)(bbase + r) * D + jbase + c];
        const float4 lo = *reinterpret_cast<const float4*>(src);
        const float4 hi = *reinterpret_cast<const float4*>(src + 4);
        *reinterpret_cast<bf16x8*>(&sP[r][c]) = cvt8(lo, hi);
    }

    // ---- hoisted epilogue cf loads (independent of LDS; overlap staging) ----
    const int lane = t & 63;
    const int wid = t >> 6;
    const int mloc = wid * 32;      // 4 waves x 32 local b-rows = 128 = BM
    const int r16 = lane & 15;      // m/n index within fragment
    const int g = lane >> 4;        // k-block for A/B; row-group for C/D

    float cfv[2][4][4];
    #pragma unroll
    for (int mf = 0; mf < 2; ++mf)
        #pragma unroll
        for (int nf = 0; nf < 4; ++nf)
            #pragma unroll
            for (int r = 0; r < 4; ++r)
                cfv[mf][nf][r] = cf[(size_t)(bbase + mloc + mf * 16 + g * 4 + r) * D
                                    + ibase + nf * 16 + r16];

    __syncthreads();

    // ---- MFMA: wave = 32 b-rows x 64 i-cols, K = JC ----
    f32x4 accG[2][4] = {};
    f32x4 accH[2][4] = {};

    #pragma unroll
    for (int ks = 0; ks < JC / 32; ++ks) {
        const int c0 = ks * 32 + g * 8;
        bf16x8 a[2], b[4];
        #pragma unroll
        for (int mf = 0; mf < 2; ++mf)
            a[mf] = *reinterpret_cast<const bf16x8*>(&sP[mloc + mf * 16 + r16][c0]);
        #pragma unroll
        for (int nf = 0; nf < 4; ++nf)
            b[nf] = *reinterpret_cast<const bf16x8*>(&sW[nf * 16 + r16][c0]);
        #pragma unroll
        for (int mf = 0; mf < 2; ++mf) {
            int32x4 ai = __builtin_bit_cast(int32x4, a[mf]);
            ai &= 0x7fff7fff;       // |pf| exactly: clear bf16 sign bits
            const bf16x8 aa = __builtin_bit_cast(bf16x8, ai);
            #pragma unroll
            for (int nf = 0; nf < 4; ++nf) {
                accG[mf][nf] = __builtin_amdgcn_mfma_f32_16x16x32_bf16(a[mf], b[nf], accG[mf][nf], 0, 0, 0);
                accH[mf][nf] = __builtin_amdgcn_mfma_f32_16x16x32_bf16(aa,    b[nf], accH[mf][nf], 0, 0, 0);
            }
        }
    }

    // ---- epilogue: C/D col=lane&15 -> i, row=(lane>>4)*4+r -> b ----
    float s[2][4];
    #pragma unroll
    for (int mf = 0; mf < 2; ++mf)
        #pragma unroll
        for (int r = 0; r < 4; ++r) s[mf][r] = 0.f;

    #pragma unroll
    for (int mf = 0; mf < 2; ++mf) {
        #pragma unroll
        for (int nf = 0; nf < 4; ++nf) {
            #pragma unroll
            for (int r = 0; r < 4; ++r) {
                const float c = cfv[mf][nf][r];
                s[mf][r] = fmaf(0.55f * c, accG[mf][nf][r],
                           fmaf(0.45f * fabsf(c), accH[mf][nf][r], s[mf][r]));
            }
        }
    }
    #pragma unroll
    for (int mf = 0; mf < 2; ++mf) {
        #pragma unroll
        for (int r = 0; r < 4; ++r) {
            float v = s[mf][r];
            v += __shfl_xor(v, 1);
            v += __shfl_xor(v, 2);
            v += __shfl_xor(v, 4);
            v += __shfl_xor(v, 8);
            s[mf][r] = v;
        }
    }
    // partials: ws[b][nt*KC+kc]; bh halves write disjoint b -> no overlap
    if (r16 == 0) {
        const int flat = nt * KC + kc;
        #pragma unroll
        for (int mf = 0; mf < 2; ++mf)
            #pragma unroll
            for (int r = 0; r < 4; ++r)
                ws[(size_t)(bbase + mloc + mf * 16 + g * 4 + r) * NPART + flat] = s[mf][r];
    }
}

// one wave per batch row: sum 256 contiguous partials + bias
__global__ __launch_bounds__(256) void opl_reduce(
    const float* __restrict__ ws, const float* __restrict__ bias,
    float* __restrict__ out)
{
    const int wid = threadIdx.x >> 6, lane = threadIdx.x & 63;
    const int b = blockIdx.x * 4 + wid;
    const float* p = ws + (size_t)b * NPART;
    float s = 0.f;
    #pragma unroll
    for (int k = 0; k < NPART / 64; ++k) s += p[lane + k * 64];
    #pragma unroll
    for (int off = 1; off < 64; off <<= 1) s += __shfl_xor(s, off);
    if (lane == 0) out[b] = s + bias[0];
}

// ---- fallback (round-1 verified pure-VALU path) if ws too small ----
__global__ __launch_bounds__(256) void opl_init_fb(float* __restrict__ out,
                                                   const float* __restrict__ bias) {
    out[threadIdx.x] = bias[0];
}

__global__ __launch_bounds__(256, 2) void opl_valu_fb(
    const float* __restrict__ cf, const float* __restrict__ pf,
    const float* __restrict__ W, float* __restrict__ out)
{
    constexpr int FBM = 64, FBN = 64, FBK = 32, FKC = 128;
    const int bid = blockIdx.x;
    const int mt = bid & 3, ntb = (bid >> 2) & 15, kcb = bid >> 6;
    const int mbase = mt * FBM, nbase = ntb * FBN, kbase = kcb * FKC;
    __shared__ float sWf[FBK][FBN];
    __shared__ float sC[FBK][FBM + 4];
    const int tid = threadIdx.x;
    const int tx = tid & 15, ty = tid >> 4;
    const int wr = tid >> 4, wc = (tid & 15) * 4;
    const int cb = tid >> 3, ci = (tid & 7) * 4;
    float accG[4][4] = {{0.f}}, accH[4][4] = {{0.f}};
    for (int k0 = 0; k0 < FKC; k0 += FBK) {
        const int kg = kbase + k0;
        const float4 w0 = *reinterpret_cast<const float4*>(&W[(size_t)(kg + wr) * D + nbase + wc]);
        const float4 w1 = *reinterpret_cast<const float4*>(&W[(size_t)(kg + wr + 16) * D + nbase + wc]);
        const float4 c0 = *reinterpret_cast<const float4*>(&cf[(size_t)(mbase + cb) * D + kg + ci]);
        const float4 c1 = *reinterpret_cast<const float4*>(&cf[(size_t)(mbase + cb + 32) * D + kg + ci]);
        *reinterpret_cast<float4*>(&sWf[wr][wc]) = w0;
        *reinterpret_cast<float4*>(&sWf[wr + 16][wc]) = w1;
        sC[ci + 0][cb] = c0.x; sC[ci + 1][cb] = c0.y;
        sC[ci + 2][cb] = c0.z; sC[ci + 3][cb] = c0.w;
        sC[ci + 0][cb + 32] = c1.x; sC[ci + 1][cb + 32] = c1.y;
        sC[ci + 2][cb + 32] = c1.z; sC[ci + 3][cb + 32] = c1.w;
        __syncthreads();
        #pragma unroll
        for (int k = 0; k < FBK; ++k) {
            const float4 wv = *reinterpret_cast<const float4*>(&sWf[k][tx * 4]);
            const float4 cv = *reinterpret_cast<const float4*>(&sC[k][ty * 4]);
            const float w[4] = {wv.x, wv.y, wv.z, wv.w};
            const float c[4] = {cv.x, cv.y, cv.z, cv.w};
            #pragma unroll
            for (int r = 0; r < 4; ++r) {
                const float cc = c[r], aa = fabsf(cc);
                #pragma unroll
                for (int q = 0; q < 4; ++q) {
                    accG[r][q] = fmaf(cc, w[q], accG[r][q]);
                    accH[r][q] = fmaf(aa, w[q], accH[r][q]);
                }
            }
        }
        __syncthreads();
    }
    float sr[4];
    #pragma unroll
    for (int r = 0; r < 4; ++r) {
        const float4 pv = *reinterpret_cast<const float4*>(&pf[(size_t)(mbase + ty * 4 + r) * D + nbase + tx * 4]);
        const float p[4] = {pv.x, pv.y, pv.z, pv.w};
        float acc = 0.f;
        #pragma unroll
        for (int q = 0; q < 4; ++q)
            acc += 0.55f * p[q] * accG[r][q] + 0.45f * fabsf(p[q]) * accH[r][q];
        sr[r] = acc;
    }
    #pragma unroll
    for (int r = 0; r < 4; ++r) {
        sr[r] += __shfl_xor(sr[r], 1);
        sr[r] += __shfl_xor(sr[r], 2);
        sr[r] += __shfl_xor(sr[r], 4);
        sr[r] += __shfl_xor(sr[r], 8);
    }
    if (tx == 0) {
        #pragma unroll
        for (int r = 0; r < 4; ++r)
            atomicAdd(&out[mbase + ty * 4 + r], sr[r]);
    }
}

extern "C" void kernel_launch(void* const* d_in, const int* in_sizes, int n_in,
                              void* d_out, int out_size, void* d_ws, size_t ws_size,
                              hipStream_t stream) {
    const float* cf   = (const float*)d_in[0];
    const float* pf   = (const float*)d_in[1];
    const float* W    = (const float*)d_in[2];
    const float* bias = (const float*)d_in[3];
    float* out = (float*)d_out;
    float* ws  = (float*)d_ws;   // B * NPART * 4 = 256 KB, fully rewritten each call

    if (ws_size >= (size_t)B * NPART * sizeof(float)) {
        opl_main<<<NBLK, 256, 0, stream>>>(cf, pf, W, ws);
        opl_reduce<<<B / 4, 256, 0, stream>>>(ws, bias, out);
    } else {
        opl_init_fb<<<1, 256, 0, stream>>>(out, bias);
        opl_valu_fb<<<512, 256, 0, stream>>>(cf, pf, W, out);
    }
}